// Round 3
// baseline (1194.014 us; speedup 1.0000x reference)
//
#include <hip/hip_runtime.h>
#include <hip/hip_bf16.h>
#include <math.h>

#define N_TASKS 200000
#define N_DATA  100000
#define N_DEV   4
#define E_TD    800000
#define E_TT    1600000
#define E_DV    800000
#define E_ALL   (E_TD + E_TT + E_DV)

struct __align__(8) Payload { int src; float scal; };

// ---- workspace layout (units: 4-byte words) ----
// hs arrays are bf16 now (half the words).
#define OFF_HS_TD   0                           // 100000*64 bf16 = 3.2M words
#define OFF_HS_TT   (OFF_HS_TD + 3200000)       // 200000*64 bf16 = 6.4M words
#define OFF_HS_DV   (OFF_HS_TT + 6400000)       // 4*64 bf16 -> 128 words
#define OFF_SS_TD   (OFF_HS_DV + 128)           // 100000
#define OFF_SS_TT   (OFF_SS_TD + 100000)        // 200000
#define OFF_SS_DV   (OFF_SS_TT + 200000)        // 8
#define OFF_WDAD    (OFF_SS_DV + 8)             // 64
#define OFF_WEA     (OFF_WDAD + 64)             // 8
#define OFF_SD      (OFF_WEA + 8)               // 600000 (sd per rel,node)
#define OFF_CNT     (OFF_SD + 600000)           // 600000  \ adjacent: single
#define OFF_DENOM   (OFF_CNT + 600000)          // 600000  / memset zeroes both
#define OFF_PTR     (OFF_DENOM + 600000)        // 600000
#define OFF_AUX     (OFF_PTR + 600000)          // 1024
#define OFF_RANGE   (OFF_AUX + 1024)            // 1200000 (int2 x 600000)
#define OFF_CURSOR  (OFF_RANGE + 1200000)       // 600000
#define OFF_PAY     (OFF_CURSOR + 600000)       // 3.2M payloads *2 words + slack
#define SCAN_N      600000
#define SCAN_BLOCKS ((SCAN_N + 1023) / 1024)    // 586

// Fold Wd@a_d (per relation, 12 floats) and We@a_e (3+1+2 floats) once.
__global__ void prep_kernel(const float* Wd_td, const float* ad_td,
                            const float* Wd_tt, const float* ad_tt,
                            const float* Wd_dv, const float* ad_dv,
                            const float* We_td, const float* ae_td,
                            const float* We_tt, const float* ae_tt,
                            const float* We_dv, const float* ae_dv,
                            float* wdad, float* wea) {
    int t = threadIdx.x;
    if (t < 36) {
        int r = t / 12, k = t % 12;
        const float* Wd = r == 0 ? Wd_td : (r == 1 ? Wd_tt : Wd_dv);
        const float* ad = r == 0 ? ad_td : (r == 1 ? ad_tt : ad_dv);
        float acc = 0.f;
        for (int c = 0; c < 64; ++c) acc += Wd[k * 64 + c] * ad[c];
        wdad[r * 12 + k] = acc;
    } else if (t < 42) {
        int i = t - 36;
        int r, k;
        if (i < 3)      { r = 0; k = i; }
        else if (i < 4) { r = 1; k = 0; }
        else            { r = 2; k = i - 4; }
        const float* We = r == 0 ? We_td : (r == 1 ? We_tt : We_dv);
        const float* ae = r == 0 ? ae_td : (r == 1 ? ae_tt : ae_dv);
        float acc = 0.f;
        for (int c = 0; c < 64; ++c) acc += We[k * 64 + c] * ae[c];
        wea[i] = acc;
    }
}

// hs = bf16(x_src @ Ws); ss = (x@Ws) @ a_s (fp32). One wave per source node.
// For the task-node instance (ds==12, sd_out!=null) also emits sd[r*N+node]
// = x_row @ wdad_r for the 3 relations (lanes 0..2).
__global__ void hs_kernel(const float* __restrict__ x, int Ns, int ds,
                          const float* __restrict__ Ws, const float* __restrict__ a_s,
                          __hip_bfloat16* __restrict__ hs, float* __restrict__ ss,
                          const float* __restrict__ wdad_all, float* __restrict__ sd_out) {
    int gid = blockIdx.x * blockDim.x + threadIdx.x;
    int s = gid >> 6;
    int lane = gid & 63;
    if (s >= Ns) return;
    float acc = 0.f;
    for (int k = 0; k < ds; ++k) acc += x[(size_t)s * ds + k] * Ws[k * 64 + lane];
    hs[(size_t)s * 64 + lane] = __float2bfloat16(acc);
    float t = acc * a_s[lane];
    for (int off = 32; off; off >>= 1) t += __shfl_down(t, off, 64);
    if (lane == 0) ss[s] = t;
    if (sd_out != nullptr && lane < 3) {
        float sd = 0.f;
        #pragma unroll
        for (int k = 0; k < 12; ++k) sd += x[(size_t)s * 12 + k] * wdad_all[lane * 12 + k];
        sd_out[lane * N_TASKS + s] = sd;
    }
}

// Merged histogram, int4-vectorized (all E divisible by 4).
__global__ void count_all(const int4* __restrict__ dst_td, const int4* __restrict__ dst_tt,
                          const int4* __restrict__ dst_dv, int* __restrict__ cnt) {
    const int QTD = E_TD / 4, QTT = E_TT / 4, QDV = E_DV / 4;
    int i = blockIdx.x * blockDim.x + threadIdx.x;
    int4 v; int base;
    if (i < QTD)            { v = dst_td[i];             base = 0; }
    else if (i < QTD + QTT) { v = dst_tt[i - QTD];       base = N_TASKS; }
    else if (i < QTD + QTT + QDV) { v = dst_dv[i - QTD - QTT]; base = 2 * N_TASKS; }
    else return;
    atomicAdd(&cnt[base + v.x], 1);
    atomicAdd(&cnt[base + v.y], 1);
    atomicAdd(&cnt[base + v.z], 1);
    atomicAdd(&cnt[base + v.w], 1);
}

// ---- 3-kernel exclusive scan over 600000 ints ----
__global__ void scan1(const int* __restrict__ cnt, int* __restrict__ ptr,
                      int* __restrict__ aux, int n) {
    __shared__ int s[256];
    int b = blockIdx.x, t = threadIdx.x;
    int base = b * 1024 + t * 4;
    int v0 = base + 0 < n ? cnt[base + 0] : 0;
    int v1 = base + 1 < n ? cnt[base + 1] : 0;
    int v2 = base + 2 < n ? cnt[base + 2] : 0;
    int v3 = base + 3 < n ? cnt[base + 3] : 0;
    int tsum = v0 + v1 + v2 + v3;
    s[t] = tsum;
    __syncthreads();
    for (int off = 1; off < 256; off <<= 1) {
        int x = (t >= off) ? s[t - off] : 0;
        __syncthreads();
        s[t] += x;
        __syncthreads();
    }
    int p = s[t] - tsum;  // exclusive prefix within block
    if (t == 255) aux[b] = s[255];
    if (base + 0 < n) ptr[base + 0] = p; p += v0;
    if (base + 1 < n) ptr[base + 1] = p; p += v1;
    if (base + 2 < n) ptr[base + 2] = p; p += v2;
    if (base + 3 < n) ptr[base + 3] = p;
}

__global__ void scan2(int* __restrict__ aux, int nb) {
    __shared__ int s[256];
    int t = threadIdx.x;
    int carry = 0;
    for (int base = 0; base < nb; base += 256) {
        int i = base + t;
        int v = i < nb ? aux[i] : 0;
        s[t] = v;
        __syncthreads();
        for (int off = 1; off < 256; off <<= 1) {
            int x = (t >= off) ? s[t - off] : 0;
            __syncthreads();
            s[t] += x;
            __syncthreads();
        }
        int excl = s[t] - v + carry;
        if (i < nb) aux[i] = excl;
        int total = s[255];
        __syncthreads();
        carry += total;
    }
}

// Finalize: range[i] = (beg, end), cursor[i] = beg.
__global__ void scan3(const int* __restrict__ ptr, const int* __restrict__ aux,
                      const int* __restrict__ cnt, int2* __restrict__ range,
                      int* __restrict__ cursor, int n) {
    int i = blockIdx.x * blockDim.x + threadIdx.x;
    if (i < n) {
        int beg = ptr[i] + aux[i >> 10];
        int c = cnt[i];
        range[i] = make_int2(beg, beg + c);
        cursor[i] = beg;
    }
}

// Merged scatter. Computes the FINAL edge weight w = exp(leaky(ss+se+sd)),
// accumulates the softmax denominator per segment, and stores (src, w).
__global__ void scatter_all(const int* __restrict__ src_td, const int* __restrict__ dst_td, const float* __restrict__ ea_td,
                            const int* __restrict__ src_tt, const int* __restrict__ dst_tt, const float* __restrict__ ea_tt,
                            const int* __restrict__ src_dv, const int* __restrict__ dst_dv, const float* __restrict__ ea_dv,
                            const float* __restrict__ wea,
                            const float* __restrict__ ss_td, const float* __restrict__ ss_tt, const float* __restrict__ ss_dv,
                            const float* __restrict__ sd,
                            int* __restrict__ cursor, float* __restrict__ denom,
                            Payload* __restrict__ payload) {
    int i = blockIdx.x * blockDim.x + threadIdx.x;
    if (i >= E_ALL) return;
    int s, dseg;
    float sc;
    if (i < E_TD) {
        int e = i;
        sc = ea_td[(size_t)e * 3 + 0] * wea[0] + ea_td[(size_t)e * 3 + 1] * wea[1] + ea_td[(size_t)e * 3 + 2] * wea[2];
        s = src_td[e];
        sc += ss_td[s];
        dseg = dst_td[e];
    } else if (i < E_TD + E_TT) {
        int e = i - E_TD;
        sc = ea_tt[e] * wea[3];
        s = src_tt[e];
        sc += ss_tt[s];
        dseg = N_TASKS + dst_tt[e];
    } else {
        int e = i - E_TD - E_TT;
        sc = ea_dv[(size_t)e * 2 + 0] * wea[4] + ea_dv[(size_t)e * 2 + 1] * wea[5];
        s = src_dv[e];
        sc += ss_dv[s];
        dseg = 2 * N_TASKS + dst_dv[e];
    }
    float lg = sc + sd[dseg];
    lg = lg > 0.f ? lg : 0.2f * lg;
    float w = __expf(lg);
    atomicAdd(&denom[dseg], w);
    int pos = atomicAdd(&cursor[dseg], 1);
    Payload p; p.src = s; p.scal = w;
    payload[pos] = p;
}

__device__ __forceinline__ void agg_accum(float4& A, float w, uint2 h) {
    A.x += w * __uint_as_float(h.x << 16);
    A.y += w * __uint_as_float(h.x & 0xffff0000u);
    A.z += w * __uint_as_float(h.y << 16);
    A.w += w * __uint_as_float(h.y & 0xffff0000u);
}

__device__ __forceinline__ void rel_chunk(const Payload* __restrict__ pay, int beg, int deg,
                                          int ia, int ib, int cg,
                                          const __hip_bfloat16* __restrict__ hs, float4& A) {
    int lim = deg - 1;
    Payload pa = pay[beg + min(ia, lim)];
    Payload pb = pay[beg + min(ib, lim)];
    const uint2* ra = (const uint2*)(hs + ((size_t)pa.src << 6));
    const uint2* rb = (const uint2*)(hs + ((size_t)pb.src << 6));
    uint2 ha = ra[cg];
    uint2 hb = rb[cg];
    float wa = (ia <= lim) ? pa.scal : 0.f;
    float wb = (ib <= lim) ? pb.scal : 0.f;
    agg_accum(A, wa, ha);
    agg_accum(A, wb, hb);
}

__device__ __forceinline__ void red_eslot(float4& A) {
    A.x += __shfl_xor(A.x, 16, 64); A.y += __shfl_xor(A.y, 16, 64);
    A.z += __shfl_xor(A.z, 16, 64); A.w += __shfl_xor(A.w, 16, 64);
    A.x += __shfl_xor(A.x, 32, 64); A.y += __shfl_xor(A.y, 32, 64);
    A.z += __shfl_xor(A.z, 32, 64); A.w += __shfl_xor(A.w, 32, 64);
}

// One WAVE per task node (4 nodes per 256-thread block). No LDS, no barriers.
// All 3 relations processed in one fused loop so their gathers overlap.
__global__ __launch_bounds__(256) void fused_node_kernel(
    const float* __restrict__ x_tasks,
    const int2* __restrict__ range,
    const float* __restrict__ denom,
    const Payload* __restrict__ payload,
    const __hip_bfloat16* __restrict__ hs_td,
    const __hip_bfloat16* __restrict__ hs_tt,
    const __hip_bfloat16* __restrict__ hs_dv,
    const float* __restrict__ Wr_td, const float* __restrict__ Wr_tt, const float* __restrict__ Wr_dv,
    const float* __restrict__ b_td, const float* __restrict__ b_tt, const float* __restrict__ b_dv,
    const float* __restrict__ ln_g, const float* __restrict__ ln_b,
    float* __restrict__ out) {
    int lane = threadIdx.x & 63;
    int d = blockIdx.x * 4 + (threadIdx.x >> 6);   // 200000 = 4*50000, exact

    // independent front loads (7 loads in flight)
    float xv = (lane < 12) ? x_tasks[(size_t)d * 12 + lane] : 0.f;
    int2 rg0 = range[d];
    int2 rg1 = range[N_TASKS + d];
    int2 rg2 = range[2 * N_TASKS + d];
    float dn0 = denom[d];
    float dn1 = denom[N_TASKS + d];
    float dn2 = denom[2 * N_TASKS + d];

    int deg0 = rg0.y - rg0.x, deg1 = rg1.y - rg1.x, deg2 = rg2.y - rg2.x;
    int eslot = lane >> 4, cg = lane & 15;
    float4 A0 = {0, 0, 0, 0}, A1 = {0, 0, 0, 0}, A2 = {0, 0, 0, 0};

    int maxdeg = max(deg0, max(deg1, deg2));
    for (int base = 0; base < maxdeg; base += 8) {   // wave-uniform trip count
        int ia = base + eslot, ib = base + 4 + eslot;
        if (base < deg0) rel_chunk(payload, rg0.x, deg0, ia, ib, cg, hs_td, A0);
        if (base < deg1) rel_chunk(payload, rg1.x, deg1, ia, ib, cg, hs_tt, A1);
        if (base < deg2) rel_chunk(payload, rg2.x, deg2, ia, ib, cg, hs_dv, A2);
    }
    red_eslot(A0); red_eslot(A1); red_eslot(A2);

    float inv0 = 1.f / (dn0 + 1e-16f);
    float inv1 = 1.f / (dn1 + 1e-16f);
    float inv2 = 1.f / (dn2 + 1e-16f);

    // broadcast x row to all lanes
    float xk[12];
    #pragma unroll
    for (int k = 0; k < 12; ++k) xk[k] = __shfl(xv, k, 64);

    // residual (x_d @ Wr + b) per relation, float4 per cg; all lanes compute
    const float4* W0 = (const float4*)Wr_td;
    const float4* W1 = (const float4*)Wr_tt;
    const float4* W2 = (const float4*)Wr_dv;
    float4 R0 = ((const float4*)b_td)[cg];
    float4 R1 = ((const float4*)b_tt)[cg];
    float4 R2 = ((const float4*)b_dv)[cg];
    #pragma unroll
    for (int k = 0; k < 12; ++k) {
        float x = xk[k];
        float4 w0 = W0[k * 16 + cg], w1 = W1[k * 16 + cg], w2 = W2[k * 16 + cg];
        R0.x += x * w0.x; R0.y += x * w0.y; R0.z += x * w0.z; R0.w += x * w0.w;
        R1.x += x * w1.x; R1.y += x * w1.y; R1.z += x * w1.z; R1.w += x * w1.w;
        R2.x += x * w2.x; R2.y += x * w2.y; R2.z += x * w2.z; R2.w += x * w2.w;
    }
    A0.x = A0.x * inv0 + R0.x; A0.y = A0.y * inv0 + R0.y; A0.z = A0.z * inv0 + R0.z; A0.w = A0.w * inv0 + R0.w;
    A1.x = A1.x * inv1 + R1.x; A1.y = A1.y * inv1 + R1.y; A1.z = A1.z * inv1 + R1.z; A1.w = A1.w * inv1 + R1.w;
    A2.x = A2.x * inv2 + R2.x; A2.y = A2.y * inv2 + R2.y; A2.z = A2.z * inv2 + R2.z; A2.w = A2.w * inv2 + R2.w;

    // LayerNorm stats over 204: x on lanes<12, A* float4 on lanes<16 (eslot 0..3
    // hold identical copies after red_eslot; count only lanes<16).
    float sum = xv, sq = xv * xv;
    if (lane < 16) {
        sum += A0.x + A0.y + A0.z + A0.w + A1.x + A1.y + A1.z + A1.w + A2.x + A2.y + A2.z + A2.w;
        sq  += A0.x*A0.x + A0.y*A0.y + A0.z*A0.z + A0.w*A0.w
             + A1.x*A1.x + A1.y*A1.y + A1.z*A1.z + A1.w*A1.w
             + A2.x*A2.x + A2.y*A2.y + A2.z*A2.z + A2.w*A2.w;
    }
    #pragma unroll
    for (int off = 1; off < 64; off <<= 1) {
        sum += __shfl_xor(sum, off, 64);
        sq  += __shfl_xor(sq, off, 64);
    }
    float mu = sum / 204.f;
    float var = sq / 204.f - mu * mu;
    float rstd = rsqrtf(var + 1e-5f);

    float* orow = out + (size_t)d * 204;
    if (lane < 12) {
        float y = (xv - mu) * rstd * ln_g[lane] + ln_b[lane];
        orow[lane] = y > 0.f ? y : 0.01f * y;
    }
    if (lane < 16) {
        #pragma unroll
        for (int r = 0; r < 3; ++r) {
            float4 A = r == 0 ? A0 : (r == 1 ? A1 : A2);
            int off = 12 + r * 64 + cg * 4;
            float4 g = *(const float4*)(ln_g + off);
            float4 bb = *(const float4*)(ln_b + off);
            float4 y;
            y.x = (A.x - mu) * rstd * g.x + bb.x;
            y.y = (A.y - mu) * rstd * g.y + bb.y;
            y.z = (A.z - mu) * rstd * g.z + bb.z;
            y.w = (A.w - mu) * rstd * g.w + bb.w;
            y.x = y.x > 0.f ? y.x : 0.01f * y.x;
            y.y = y.y > 0.f ? y.y : 0.01f * y.y;
            y.z = y.z > 0.f ? y.z : 0.01f * y.z;
            y.w = y.w > 0.f ? y.w : 0.01f * y.w;
            *(float4*)(orow + off) = y;
        }
    }
}

extern "C" void kernel_launch(void* const* d_in, const int* in_sizes, int n_in,
                              void* d_out, int out_size, void* d_ws, size_t ws_size,
                              hipStream_t stream) {
    const float* x_tasks   = (const float*)d_in[0];
    const float* x_data    = (const float*)d_in[1];
    const float* x_devices = (const float*)d_in[2];
    const int*   src_td = (const int*)d_in[3];
    const int*   dst_td = (const int*)d_in[4];
    const float* eattr_td = (const float*)d_in[5];
    const int*   src_tt = (const int*)d_in[6];
    const int*   dst_tt = (const int*)d_in[7];
    const float* eattr_tt = (const float*)d_in[8];
    const int*   src_dv = (const int*)d_in[9];
    const int*   dst_dv = (const int*)d_in[10];
    const float* eattr_dv = (const float*)d_in[11];
    const float* Ws_td = (const float*)d_in[12];
    const float* Wd_td = (const float*)d_in[13];
    const float* We_td = (const float*)d_in[14];
    const float* as_td = (const float*)d_in[15];
    const float* ad_td = (const float*)d_in[16];
    const float* ae_td = (const float*)d_in[17];
    const float* Wr_td = (const float*)d_in[18];
    const float* b_td  = (const float*)d_in[19];
    const float* Ws_tt = (const float*)d_in[20];
    const float* Wd_tt = (const float*)d_in[21];
    const float* We_tt = (const float*)d_in[22];
    const float* as_tt = (const float*)d_in[23];
    const float* ad_tt = (const float*)d_in[24];
    const float* ae_tt = (const float*)d_in[25];
    const float* Wr_tt = (const float*)d_in[26];
    const float* b_tt  = (const float*)d_in[27];
    const float* Ws_dv = (const float*)d_in[28];
    const float* Wd_dv = (const float*)d_in[29];
    const float* We_dv = (const float*)d_in[30];
    const float* as_dv = (const float*)d_in[31];
    const float* ad_dv = (const float*)d_in[32];
    const float* ae_dv = (const float*)d_in[33];
    const float* Wr_dv = (const float*)d_in[34];
    const float* b_dv  = (const float*)d_in[35];
    const float* ln_g  = (const float*)d_in[36];
    const float* ln_b  = (const float*)d_in[37];

    float* ws = (float*)d_ws;
    __hip_bfloat16* hs_td = (__hip_bfloat16*)(ws + OFF_HS_TD);
    __hip_bfloat16* hs_tt = (__hip_bfloat16*)(ws + OFF_HS_TT);
    __hip_bfloat16* hs_dv = (__hip_bfloat16*)(ws + OFF_HS_DV);
    float* ss_td = ws + OFF_SS_TD;
    float* ss_tt = ws + OFF_SS_TT;
    float* ss_dv = ws + OFF_SS_DV;
    float* wdad  = ws + OFF_WDAD;
    float* wea   = ws + OFF_WEA;
    float* sd    = ws + OFF_SD;
    int*   cnt   = (int*)(ws + OFF_CNT);
    float* denom = ws + OFF_DENOM;
    int*   ptr   = (int*)(ws + OFF_PTR);
    int*   aux   = (int*)(ws + OFF_AUX);
    int2*  range = (int2*)(ws + OFF_RANGE);
    int*   cursor = (int*)(ws + OFF_CURSOR);
    Payload* pay = (Payload*)(ws + OFF_PAY);

    float* outp = (float*)d_out;

    // zero cnt + denom (adjacent) in one memset
    hipMemsetAsync(cnt, 0, 2 * SCAN_N * sizeof(int), stream);

    prep_kernel<<<1, 64, 0, stream>>>(Wd_td, ad_td, Wd_tt, ad_tt, Wd_dv, ad_dv,
                                      We_td, ae_td, We_tt, ae_tt, We_dv, ae_dv,
                                      wdad, wea);

    hs_kernel<<<(N_DATA * 64 + 255) / 256, 256, 0, stream>>>(x_data, N_DATA, 5, Ws_td, as_td, hs_td, ss_td, nullptr, nullptr);
    hs_kernel<<<(N_TASKS * 64 + 255) / 256, 256, 0, stream>>>(x_tasks, N_TASKS, 12, Ws_tt, as_tt, hs_tt, ss_tt, wdad, sd);
    hs_kernel<<<1, 256, 0, stream>>>(x_devices, N_DEV, 12, Ws_dv, as_dv, hs_dv, ss_dv, nullptr, nullptr);

    count_all<<<(E_ALL / 4 + 255) / 256, 256, 0, stream>>>(
        (const int4*)dst_td, (const int4*)dst_tt, (const int4*)dst_dv, cnt);

    scan1<<<SCAN_BLOCKS, 256, 0, stream>>>(cnt, ptr, aux, SCAN_N);
    scan2<<<1, 256, 0, stream>>>(aux, SCAN_BLOCKS);
    scan3<<<(SCAN_N + 255) / 256, 256, 0, stream>>>(ptr, aux, cnt, range, cursor, SCAN_N);

    scatter_all<<<(E_ALL + 255) / 256, 256, 0, stream>>>(
        src_td, dst_td, eattr_td, src_tt, dst_tt, eattr_tt, src_dv, dst_dv, eattr_dv,
        wea, ss_td, ss_tt, ss_dv, sd, cursor, denom, pay);

    fused_node_kernel<<<N_TASKS / 4, 256, 0, stream>>>(
        x_tasks, range, denom, pay, hs_td, hs_tt, hs_dv,
        Wr_td, Wr_tt, Wr_dv, b_td, b_tt, b_dv, ln_g, ln_b, outp);
}